// Round 3
// baseline (813.512 us; speedup 1.0000x reference)
//
#include <hip/hip_runtime.h>

// Problem: relu(quant8(x) @ quant8(W)^T + bias)
//   x: [2,2048,4096] f32  -> M=4096, K=4096
//   W: [16384,4096]  f32  -> N=16384 (row-major in K, i.e. B^T layout)
//   out: [2,2048,16384] f32
//
// R4 change: occupancy fix. R3 null (LDS-traffic cut changed nothing) refuted
// the LDS-BW theory; counters showed 1 workgroup/CU (Occupancy 22.7% = 8
// waves = one 512-thread block) -> every per-phase stall (lgkm tail, barrier
// skew, far-L2/LLC b-load latency) hit a matrix pipe with no independent
// waves to fill it. Fix: BM 256->128, 256 threads = 4 waves, per-wave work
// identical (128x64 out, 64 MFMA/K-tile). LDS 64->32 KiB, regs ~248/wave
// -> TWO independent workgroups co-resident per CU (m114 async-overlap
// mechanism): block X's barrier/latency gaps are filled by block Y's MFMAs.
// Schedule, vmcnt ledger, swizzles carried over unchanged from R3:
//   ph1: ds_read A-lo (8xb128); load b1(T);            MFMA q00 (a0*b0)
//   ph2: stage A-lo(T+2) (2 GLL);                      MFMA q01 (a0*b1)
//   ph3: ds_read A-hi (8xb128);                        MFMA q10 (a1*b0)
//   ph4: load b0(T+1); stage A-hi(T+2); vmcnt(12);     MFMA q11 (a1*b1)
// each phase: [reads/stages]; barrier; [lgkm]; setprio(1); MFMA; setprio(0); barrier
// vmcnt(12) = this tile's 12 vm ops {b1:4, GLL:2, b0:4, GLL:2} -> everything
// older (incl. tile T+1's A stages) retired; never drains in main loop.
// Secondary: pack-B stores widened 4B->16B dwordx4 (R3's scatter cost ~17us).

#define HIDDEN 4096
#define INTER 16384
#define MDIM 4096
#define BK 128
#define NT (HIDDEN / BK)   // 32 K-tiles

typedef int v4i __attribute__((ext_vector_type(4)));

// ---------------------------------------------------------------------------
// Quantize A: q = round_ne(clamp(x, -c, c) * 127/c), packed 4 int8 per int32,
// linear layout (A is LDS-staged in the GEMM).
// ---------------------------------------------------------------------------
__global__ __launch_bounds__(256) void quantize_kernel(
    const float* __restrict__ x,
    signed char* __restrict__ q,
    const float* __restrict__ clip_ptr,
    int n4)
{
    int i = blockIdx.x * blockDim.x + threadIdx.x;
    if (i >= n4) return;
    float c = fabsf(clip_ptr[0]);
    float inv_scale = 127.0f / c;
    float4 v = reinterpret_cast<const float4*>(x)[i];
    int q0 = __float2int_rn(fminf(fmaxf(v.x, -c), c) * inv_scale);
    int q1 = __float2int_rn(fminf(fmaxf(v.y, -c), c) * inv_scale);
    int q2 = __float2int_rn(fminf(fmaxf(v.z, -c), c) * inv_scale);
    int q3 = __float2int_rn(fminf(fmaxf(v.w, -c), c) * inv_scale);
    int pack = (q0 & 0xff) | ((q1 & 0xff) << 8) | ((q2 & 0xff) << 16) | (q3 << 24);
    reinterpret_cast<int*>(q)[i] = pack;
}

// ---------------------------------------------------------------------------
// Quantize + pack B into MFMA-fragment order, 16-B stores.
// Frag (nf = n>>4, kf = k>>6) is 1024 B; element (n,k) -> byte offset:
//   ((n>>4)<<16) | ((k>>6)<<10) | (((k>>4)&3)<<8) | ((n&15)<<4) | (k&15)
// Thread i handles (n = i>>8, k = (i&255)*16): reads 4 consecutive float4
// (64 B contiguous per lane, row-coalesced across lanes), writes ONE aligned
// dwordx4 at the packed address (k&15 == 0 -> 16-B slot owned wholly).
// Bit-identical output to the R3 packer.
// ---------------------------------------------------------------------------
__global__ __launch_bounds__(256) void quantize_pack_b_kernel(
    const float* __restrict__ x,
    signed char* __restrict__ qp,
    const float* __restrict__ clip_ptr,
    int n16)
{
    int i = blockIdx.x * blockDim.x + threadIdx.x;
    if (i >= n16) return;
    float c = fabsf(clip_ptr[0]);
    float inv_scale = 127.0f / c;
    int n = i >> 8;               // row (HIDDEN/16 = 256 slots per row)
    int k = (i & 255) << 4;       // first k of this 16-byte slot
    const float4* src = reinterpret_cast<const float4*>(x + (size_t)n * HIDDEN + k);
    int pk[4];
#pragma unroll
    for (int j = 0; j < 4; j++) {
        float4 v = src[j];
        int q0 = __float2int_rn(fminf(fmaxf(v.x, -c), c) * inv_scale);
        int q1 = __float2int_rn(fminf(fmaxf(v.y, -c), c) * inv_scale);
        int q2 = __float2int_rn(fminf(fmaxf(v.z, -c), c) * inv_scale);
        int q3 = __float2int_rn(fminf(fmaxf(v.w, -c), c) * inv_scale);
        pk[j] = (q0 & 0xff) | ((q1 & 0xff) << 8) | ((q2 & 0xff) << 16) | (q3 << 24);
    }
    size_t addr = ((size_t)(n >> 4) << 16) | ((size_t)(k >> 6) << 10)
                | ((size_t)((k >> 4) & 3) << 8) | ((size_t)(n & 15) << 4);
    *reinterpret_cast<v4i*>(qp + addr) = *reinterpret_cast<v4i*>(pk);
}

// ---------------------------------------------------------------------------
// i8 GEMM, 128x256 tile, 256 threads = 4 waves (1M x 4N), 2 blocks/CU.
// Per wave: 128 M-rows x 64 N-cols as 2(qm) x 2(qn) x 4(m) x 2(n) 16x16 frags.
// A: LDS double-buffered (2 x 16 KiB). B: direct global->VGPR from packed qB.
// ---------------------------------------------------------------------------

#define GLL(src, dst) __builtin_amdgcn_global_load_lds( \
    (const __attribute__((address_space(1))) void*)(src), \
    (__attribute__((address_space(3))) void*)(dst), 16, 0, 0)

// one A half-tile = 64 rows x 128 B = 2 issues of (256 threads x 16 B)
#define STAGE_HALF(gptr, lptr) do { \
    GLL((gptr), (lptr)); \
    GLL((gptr) + (size_t)32 * HIDDEN, (lptr) + 4096); } while (0)

#define BARX() __builtin_amdgcn_s_barrier()
#define LGKM0() asm volatile("s_waitcnt lgkmcnt(0)" ::: "memory")
#define VM12() asm volatile("s_waitcnt vmcnt(12)" ::: "memory")
#define VM8() asm volatile("s_waitcnt vmcnt(8)" ::: "memory")
#define VMNOP()
#define PRIO1() __builtin_amdgcn_s_setprio(1)
#define PRIO0() __builtin_amdgcn_s_setprio(0)

#define READ_A(cb, qm) do { _Pragma("unroll") \
    for (int m_ = 0; m_ < 4; m_++) { \
      const signed char* p_ = &As[cb][(qm) * 8192 + aOff + m_ * 2048]; \
      a[m_][0] = *reinterpret_cast<const v4i*>(p_ + c0); \
      a[m_][1] = *reinterpret_cast<const v4i*>(p_ + c1); } } while (0)

// b-frags for quadrant-column qn of tile with kf0 = T*2: 4 coalesced dwordx4.
#define LOADB(dst, qn, kf0) do { _Pragma("unroll") \
    for (int n_ = 0; n_ < 2; n_++) { _Pragma("unroll") \
      for (int kk_ = 0; kk_ < 2; kk_++) { \
        dst[n_][kk_] = *reinterpret_cast<const v4i*>( \
            bpw + (((size_t)((qn) * 8 + n_) << 16) | \
                   ((size_t)((kf0) + kk_) << 10)) + L16); } } } while (0)

// 16 MFMA, k0-sweep then k1-sweep (keeps dependent pairs 8 apart).
#define MFMA_Q(qm, qn, bset) do { _Pragma("unroll") \
    for (int m_ = 0; m_ < 4; m_++) { _Pragma("unroll") \
      for (int n_ = 0; n_ < 2; n_++) \
        acc[qm][qn][m_][n_] = __builtin_amdgcn_mfma_i32_16x16x64_i8( \
            a[m_][0], bset[n_][0], acc[qm][qn][m_][n_], 0, 0, 0); } \
    _Pragma("unroll") \
    for (int m_ = 0; m_ < 4; m_++) { _Pragma("unroll") \
      for (int n_ = 0; n_ < 2; n_++) \
        acc[qm][qn][m_][n_] = __builtin_amdgcn_mfma_i32_16x16x64_i8( \
            a[m_][1], bset[n_][1], acc[qm][qn][m_][n_], 0, 0, 0); } } while (0)

// One K-tile group. cb = LDS buffer of tile T (= T&1).
// S2: stage A(T+2).  SB: load b0(T+1) at ph4.  VMW: pacing wait at ph4.
#define GROUP(cb, T, S2, SB, VMW) do { \
    /* ph1: q00 (a0*b0); read A-lo; prefetch b1(T) */ \
    READ_A(cb, 0); \
    LOADB(b1, 1, (T) * 2); \
    BARX(); LGKM0(); PRIO1(); MFMA_Q(0, 0, b0); PRIO0(); BARX(); \
    /* ph2: q01 (a0*b1); A-lo region retired -> stage A-lo(T+2) */ \
    if (S2) STAGE_HALF(gA + (size_t)((T) + 2) * BK, &As[cb][0] + ldsT); \
    BARX(); PRIO1(); MFMA_Q(0, 1, b1); PRIO0(); BARX(); \
    /* ph3: q10 (a1*b0); read A-hi */ \
    READ_A(cb, 1); \
    BARX(); LGKM0(); PRIO1(); MFMA_Q(1, 0, b0); PRIO0(); BARX(); \
    /* ph4: q11 (a1*b1); prefetch b0(T+1); A-hi retired -> stage A-hi(T+2) */ \
    if (SB) LOADB(b0, 0, ((T) + 1) * 2); \
    if (S2) STAGE_HALF(gA + (size_t)64 * HIDDEN + (size_t)((T) + 2) * BK, \
                       &As[cb][8192] + ldsT); \
    VMW(); \
    BARX(); PRIO1(); MFMA_Q(1, 1, b1); PRIO0(); BARX(); \
  } while (0)

__global__ __launch_bounds__(256, 2) void gemm_i8_kernel(
    const signed char* __restrict__ qA,   // [MDIM, HIDDEN] linear
    const signed char* __restrict__ Bp,   // packed frag-order [1024][64][1024B]
    const float* __restrict__ bias,       // [INTER]
    const float* __restrict__ wclip,
    const float* __restrict__ iclip,
    float* __restrict__ out)              // [MDIM, INTER]
{
    // A only, double-buffered: 2 x 16 KiB = 32 KiB -> 2 blocks/CU
    __shared__ __align__(16) signed char As[2][16384];

    const int t = threadIdx.x;
    const int L = t & 63;
    const int W = t >> 6;          // wave 0..3
    const int wn = W;              // N-quadrant owner
    const int lane16 = L & 15;
    const int quad = L >> 4;
    const int swz = lane16 & 7;
    const int L16 = L * 16;

    // XCD-aware bijective swizzle (nwg = 2048, 2048 % 8 == 0): each XCD gets
    // a contiguous 256-block chunk (4 M-rows x 64 N) -> A-panel L2 reuse.
    int wg = blockIdx.y * 64 + blockIdx.x;
    wg = (wg & 7) * 256 + (wg >> 3);
    const int mBase = (wg >> 6) * 128;
    const int nBase = (wg & 63) * 256;

    // A staging: thread t covers row (t>>3) (of a 32-row issue), physical
    // chunk (t&7); source column pre-swizzled (logical = (t&7) ^ (row&7)).
    const int sRow = t >> 3;                         // 0..31
    const int sColSwz = ((t & 7) ^ (sRow & 7)) * 16;
    const signed char* gA = qA + (size_t)(mBase + sRow) * HIDDEN + sColSwz;
    const int ldsT = t * 16;

    // A fragment read offsets (row&7 == lane16&7 for every fragment row).
    const int aOff = lane16 * 128;
    const int c0 = (quad ^ swz) * 16;
    const int c1 = ((quad + 4) ^ swz) * 16;

    // packed-B wave base: nf = nBase/16 + qn*8 + wn*2 + n
    const signed char* bpw = Bp + ((size_t)((nBase >> 4) + wn * 2) << 16);

    v4i acc[2][2][4][2];
#pragma unroll
    for (int i = 0; i < 2; i++)
#pragma unroll
        for (int j = 0; j < 2; j++)
#pragma unroll
            for (int m = 0; m < 4; m++)
#pragma unroll
                for (int n = 0; n < 2; n++)
                    acc[i][j][m][n] = (v4i){0, 0, 0, 0};

    v4i a[4][2], b0[2][2], b1[2][2];

    // Prologue: stage A tiles 0 and 1 (8 GLL), prefetch b0(tile0).
    // vmcnt(8) retires tile0's 4 GLL; tile1's 4 GLL + 4 b-loads in flight.
    STAGE_HALF(gA,                              &As[0][0]    + ldsT);  // t0-lo
    STAGE_HALF(gA + (size_t)64 * HIDDEN,        &As[0][8192] + ldsT);  // t0-hi
    STAGE_HALF(gA + BK,                         &As[1][0]    + ldsT);  // t1-lo
    STAGE_HALF(gA + (size_t)64 * HIDDEN + BK,   &As[1][8192] + ldsT);  // t1-hi
    LOADB(b0, 0, 0);
    VM8();
    BARX();

    // Main loop: groups 0..29 fully pipelined (vmcnt never drained).
    for (int T = 0; T < NT - 2; T += 2) {
        GROUP(0, T,     1, 1, VM12);
        GROUP(1, T + 1, 1, 1, VM12);
    }
    // Group NT-2: no staging left -> tighter pacing guards A(NT-1).
    GROUP(0, NT - 2, 0, 1, VM8);
    // Last group: nothing in flight to pace.
    GROUP(1, NT - 1, 0, 0, VMNOP);

    // Epilogue: out = relu(acc * (|wc|/127)*(|ic|/127) + bias)
    const float scale = (fabsf(wclip[0]) / 127.0f) * (fabsf(iclip[0]) / 127.0f);

    float bv[2][2];
#pragma unroll
    for (int qn = 0; qn < 2; qn++)
#pragma unroll
        for (int n = 0; n < 2; n++)
            bv[qn][n] = bias[nBase + qn * 128 + wn * 32 + n * 16 + lane16];

    // C/D mapping (guide-verified, dtype-independent): col = lane&15,
    // row = quad*4 + reg.
#pragma unroll
    for (int qm = 0; qm < 2; qm++)
#pragma unroll
        for (int m = 0; m < 4; m++)
#pragma unroll
            for (int r = 0; r < 4; r++) {
                const int row = mBase + qm * 64 + m * 16 + quad * 4 + r;
                float* orow = out + (size_t)row * INTER + nBase + wn * 32 + lane16;
#pragma unroll
                for (int qn = 0; qn < 2; qn++)
#pragma unroll
                    for (int n = 0; n < 2; n++) {
                        float v = (float)acc[qm][qn][m][n][r] * scale + bv[qn][n];
                        orow[qn * 128 + n * 16] = fmaxf(v, 0.0f);
                    }
            }
}

extern "C" void kernel_launch(void* const* d_in, const int* in_sizes, int n_in,
                              void* d_out, int out_size, void* d_ws, size_t ws_size,
                              hipStream_t stream) {
    const float* hidden_states  = (const float*)d_in[0];  // [2,2048,4096]
    const float* weight         = (const float*)d_in[1];  // [16384,4096]
    const float* bias           = (const float*)d_in[2];  // [16384]
    const float* weight_clip    = (const float*)d_in[3];  // scalar
    const float* input_clip     = (const float*)d_in[4];  // scalar
    float* out = (float*)d_out;

    signed char* qA = (signed char*)d_ws;                         // 16 MiB
    signed char* Bp = qA + (size_t)MDIM * HIDDEN;                 // 64 MiB packed

    // Quantize activations (linear): 4096*4096 / 4 elems per thread
    {
        int n4 = MDIM * HIDDEN / 4;
        quantize_kernel<<<n4 / 256, 256, 0, stream>>>(hidden_states, qA, input_clip, n4);
    }
    // Quantize + pack weights: 16384*4096 / 16 elems per thread (16-B stores)
    {
        int n16 = INTER * HIDDEN / 16;
        quantize_pack_b_kernel<<<n16 / 256, 256, 0, stream>>>(weight, Bp, weight_clip, n16);
    }

    dim3 grid(INTER / 256, MDIM / 128);   // 64 x 32 = 2048 blocks
    gemm_i8_kernel<<<grid, 256, 0, stream>>>(qA, Bp, bias, weight_clip, input_clip, out);
}